// Round 2
// baseline (819.350 us; speedup 1.0000x reference)
//
#include <hip/hip_runtime.h>
#include <hip/hip_bf16.h>

#define DIN 128
#define DH 32
#define DOUT 2

// ---------------------------------------------------------------------------
// workspace layout (floats), sized to fit ws_size:
//   dinv [n]      (holds deg first, rsqrt'd in place)
//   m2q  [n*2]    (layer-2 self messages, accumulated across chunks)
//   mqc  [n*C]    (chunk of scaled layer-1 messages)
//   aggc [n*C]    (chunk of layer-1 aggregation)
// total = n*(3 + 2*C) floats.  C in {32,16,8,4,2,1} chosen from ws_size.
// ---------------------------------------------------------------------------

// 1. deg=1 (self-loop), m2q=0, out=0  (ws/out poisoned 0xAA before every call)
__global__ void pre_kernel(float* __restrict__ deg, float* __restrict__ m2q,
                           float* __restrict__ out, int n) {
    int i = blockIdx.x * blockDim.x + threadIdx.x;
    if (i < n) deg[i] = 1.0f;
    if (i < n * DOUT) { m2q[i] = 0.0f; out[i] = 0.0f; }
}

// 2. degree accumulation over dst (into dinv buffer)
__global__ void deg_kernel(const int* __restrict__ dst, float* __restrict__ deg, int e) {
    int i = blockIdx.x * blockDim.x + threadIdx.x;
    if (i < e) atomicAdd(&deg[dst[i]], 1.0f);
}

// 3. dinv = rsqrt(deg), in place
__global__ void dinv_kernel(float* __restrict__ dinv, int n) {
    int i = blockIdx.x * blockDim.x + threadIdx.x;
    if (i < n) dinv[i] = rsqrtf(dinv[i]);
}

// 4. mqc[r][c] = (sum_k x[r][k] * W1[k][c0+c]) * dinv[r]; also aggc[r][c]=0
//    block = 256 = 8 rows x 32 lanes; lanes >= C idle during compute.
__global__ void gemm_chunk_kernel(const float* __restrict__ x, const float* __restrict__ W1,
                                  const float* __restrict__ dinv,
                                  float* __restrict__ mqc, float* __restrict__ aggc,
                                  int n, int C, int c0) {
    __shared__ float Wl[DIN * DH];   // [k][c] for this chunk, ld = C
    __shared__ float Xl[8][DIN];

    for (int i = threadIdx.x; i < DIN * C; i += 256) {
        int k = i / C, c = i - k * C;
        Wl[i] = W1[k * DH + c0 + c];
    }

    const int lane = threadIdx.x & 31;
    const int lr   = threadIdx.x >> 5;   // 0..7
    int rb = blockIdx.x * 8;

    for (int t = threadIdx.x; t < 8 * DIN; t += 256) {
        int rr = t >> 7, kk = t & 127;
        int gr = rb + rr;
        Xl[rr][kk] = (gr < n) ? x[(size_t)gr * DIN + kk] : 0.0f;
    }
    __syncthreads();

    int r = rb + lr;
    if (r < n && lane < C) {
        float acc = 0.0f;
#pragma unroll
        for (int k = 0; k < DIN; ++k) acc += Xl[lr][k] * Wl[k * C + lane];
        size_t o = (size_t)r * C + lane;
        mqc[o]  = acc * dinv[r];
        aggc[o] = 0.0f;
    }
}

// 5. scatter chunk: aggc[dst[e]][c] += mqc[src[e]][c]
__global__ void scatter_chunk_kernel(const int* __restrict__ src, const int* __restrict__ dst,
                                     const float* __restrict__ mqc, float* __restrict__ aggc,
                                     int e, int shiftC) {
    long long idx = (long long)blockIdx.x * blockDim.x + threadIdx.x;
    long long total = (long long)e << shiftC;
    if (idx >= total) return;
    int ei = (int)(idx >> shiftC);
    int c  = (int)(idx & ((1 << shiftC) - 1));
    int s = src[ei];
    int d = dst[ei];
    atomicAdd(&aggc[((size_t)d << shiftC) + c], mqc[((size_t)s << shiftC) + c]);
}

// 6. combine chunk: h_j = relu(dinv*(aggc+mqc) + b1[j]) for j in chunk;
//    m2q[r][o] += dinv[r] * sum_j h_j * W2[j][o]
//    C consecutive lanes per row; shuffle-reduce width C.
__global__ void combine_chunk_kernel(const float* __restrict__ aggc,
                                     const float* __restrict__ mqc,
                                     const float* __restrict__ dinv,
                                     const float* __restrict__ b1,
                                     const float* __restrict__ W2,
                                     float* __restrict__ m2q,
                                     int n, int C, int shiftC, int c0) {
    long long idx = (long long)blockIdx.x * blockDim.x + threadIdx.x;
    long long total = (long long)n << shiftC;
    if (idx >= total) return;
    int r = (int)(idx >> shiftC);
    int c = (int)(idx & (C - 1));
    int j = c0 + c;
    float di = dinv[r];
    float h = di * (aggc[idx] + mqc[idx]) + b1[j];
    h = fmaxf(h, 0.0f);
    float p0 = h * W2[j * DOUT + 0];
    float p1 = h * W2[j * DOUT + 1];
    for (int off = C >> 1; off > 0; off >>= 1) {
        p0 += __shfl_down(p0, off, C);
        p1 += __shfl_down(p1, off, C);
    }
    if (c == 0) {
        m2q[(size_t)r * DOUT + 0] += di * p0;
        m2q[(size_t)r * DOUT + 1] += di * p1;
    }
}

// 7. scatter2: out[dst[e]][o] += m2q[src[e]][o]   (out pre-zeroed)
__global__ void scatter2_kernel(const int* __restrict__ src, const int* __restrict__ dst,
                                const float* __restrict__ m2q, float* __restrict__ out,
                                int e) {
    long long idx = (long long)blockIdx.x * blockDim.x + threadIdx.x;
    long long total = (long long)e * DOUT;
    if (idx >= total) return;
    int ei = (int)(idx >> 1);
    int c  = (int)(idx & 1);
    int s = src[ei];
    int d = dst[ei];
    atomicAdd(&out[(size_t)d * DOUT + c], m2q[(size_t)s * DOUT + c]);
}

// 8. out = dinv*(out + m2q) + b2, in place
__global__ void final_kernel(float* __restrict__ out, const float* __restrict__ m2q,
                             const float* __restrict__ dinv, const float* __restrict__ b2,
                             int n) {
    int i = blockIdx.x * blockDim.x + threadIdx.x;
    if (i >= n * DOUT) return;
    int r = i >> 1, c = i & 1;
    out[i] = dinv[r] * (out[i] + m2q[i]) + b2[c];
}

extern "C" void kernel_launch(void* const* d_in, const int* in_sizes, int n_in,
                              void* d_out, int out_size, void* d_ws, size_t ws_size,
                              hipStream_t stream) {
    const float* x  = (const float*)d_in[0];
    const int*   ei = (const int*)d_in[1];   // [2, E] int32
    const float* W1 = (const float*)d_in[2];
    const float* b1 = (const float*)d_in[3];
    const float* W2 = (const float*)d_in[4];
    const float* b2 = (const float*)d_in[5];
    float* out = (float*)d_out;

    const int n = in_sizes[0] / DIN;   // 100000
    const int e = in_sizes[1] / 2;     // 3200000
    const int* src = ei;
    const int* dst = ei + e;

    // choose largest chunk width C fitting ws_size (constant across calls)
    int C = 1, shiftC = 0;
    for (int c = 32, s = 5; c >= 1; c >>= 1, --s) {
        size_t need = (size_t)n * (3 + 2 * (size_t)c) * sizeof(float);
        if (need <= ws_size) { C = c; shiftC = s; break; }
    }

    float* ws   = (float*)d_ws;
    float* dinv = ws;                          // n  (deg -> dinv)
    float* m2q  = dinv + n;                    // 2n
    float* mqc  = m2q + (size_t)n * DOUT;      // C*n
    float* aggc = mqc + (size_t)n * C;         // C*n

    const int B = 256;

    pre_kernel<<<(n * DOUT + B - 1) / B, B, 0, stream>>>(dinv, m2q, out, n);
    deg_kernel<<<(e + B - 1) / B, B, 0, stream>>>(dst, dinv, e);
    dinv_kernel<<<(n + B - 1) / B, B, 0, stream>>>(dinv, n);

    for (int c0 = 0; c0 < DH; c0 += C) {
        gemm_chunk_kernel<<<(n + 7) / 8, B, 0, stream>>>(x, W1, dinv, mqc, aggc, n, C, c0);
        long long t1 = (long long)e << shiftC;
        scatter_chunk_kernel<<<(int)((t1 + B - 1) / B), B, 0, stream>>>(src, dst, mqc, aggc, e, shiftC);
        long long t2 = (long long)n << shiftC;
        combine_chunk_kernel<<<(int)((t2 + B - 1) / B), B, 0, stream>>>(aggc, mqc, dinv, b1, W2, m2q,
                                                                        n, C, shiftC, c0);
    }

    long long t3 = (long long)e * DOUT;
    scatter2_kernel<<<(int)((t3 + B - 1) / B), B, 0, stream>>>(src, dst, m2q, out, e);
    final_kernel<<<(n * DOUT + B - 1) / B, B, 0, stream>>>(out, m2q, dinv, b2, n);
}

// Round 3
// 638.080 us; speedup vs baseline: 1.2841x; 1.2841x over previous
//
#include <hip/hip_runtime.h>
#include <hip/hip_bf16.h>

#define DIN 128
#define DH 32
#define DOUT 2

// ---------------------------------------------------------------------------
// workspace (21.2 MB, budget is ~26.8 MB):
//   cnt     int[n]     in-degree (excl self)
//   cursor  int[n]     exclusive scan of cnt; after fill = end offsets
//   bsum    int[256]   scan block sums
//   esorted int[E]     src ids bucketed by dst
//   dinv    float[n]
//   m2q     float2[n]  layer-2 self messages (dinv-scaled)
//   mqc     bf16[n*32] layer-1 messages (dinv-scaled), bf16 storage
// ---------------------------------------------------------------------------

__device__ inline unsigned short f2bf(float f) {     // RNE fp32 -> bf16 bits
    unsigned int u = __float_as_uint(f);
    u = (u + 0x7FFFu + ((u >> 16) & 1u)) >> 16;
    return (unsigned short)u;
}
__device__ inline float bf2f(unsigned short b) {
    return __uint_as_float(((unsigned int)b) << 16);
}

__global__ void zero_cnt_kernel(int* __restrict__ cnt, int n) {
    int i = blockIdx.x * blockDim.x + threadIdx.x;
    if (i < n) cnt[i] = 0;
}

__global__ void hist_kernel(const int* __restrict__ dst, int* __restrict__ cnt, int e) {
    int i = blockIdx.x * blockDim.x + threadIdx.x;
    if (i < e) atomicAdd(&cnt[dst[i]], 1);
}

// block scans 1024 elems (256 thr x 4); also emits dinv = rsqrt(cnt+1)
__global__ void scanA_kernel(const int* __restrict__ cnt, int* __restrict__ cursor,
                             int* __restrict__ bsum, float* __restrict__ dinv, int n) {
    __shared__ int sd[256];
    int t = threadIdx.x;
    int base = blockIdx.x * 1024 + t * 4;
    int v[4], s = 0;
#pragma unroll
    for (int k = 0; k < 4; ++k) {
        int i = base + k;
        v[k] = (i < n) ? cnt[i] : 0;
        s += v[k];
        if (i < n) dinv[i] = rsqrtf((float)(v[k] + 1));
    }
    sd[t] = s;
    __syncthreads();
    for (int off = 1; off < 256; off <<= 1) {
        int x = (t >= off) ? sd[t - off] : 0;
        __syncthreads();
        sd[t] += x;
        __syncthreads();
    }
    if (t == 255) bsum[blockIdx.x] = sd[255];
    int run = sd[t] - s;   // exclusive prefix within block
#pragma unroll
    for (int k = 0; k < 4; ++k) {
        int i = base + k;
        if (i < n) cursor[i] = run;
        run += v[k];
    }
}

__global__ void scanB_kernel(int* __restrict__ bsum, int nb) {
    __shared__ int sd[256];
    int t = threadIdx.x;
    int v = (t < nb) ? bsum[t] : 0;
    sd[t] = v;
    __syncthreads();
    for (int off = 1; off < 256; off <<= 1) {
        int x = (t >= off) ? sd[t - off] : 0;
        __syncthreads();
        sd[t] += x;
        __syncthreads();
    }
    if (t < nb) bsum[t] = sd[t] - v;   // exclusive
}

__global__ void scanC_kernel(int* __restrict__ cursor, const int* __restrict__ bsum, int n) {
    int add = bsum[blockIdx.x];
    int base = blockIdx.x * 1024 + threadIdx.x * 4;
#pragma unroll
    for (int k = 0; k < 4; ++k) {
        int i = base + k;
        if (i < n) cursor[i] += add;
    }
}

// bucket edges by dst: esorted[start[dst]..] = src.  cursor -> end offsets.
__global__ void fill_kernel(const int* __restrict__ src, const int* __restrict__ dst,
                            int* __restrict__ cursor, int* __restrict__ esorted, int e) {
    int i = blockIdx.x * blockDim.x + threadIdx.x;
    if (i < e) {
        int p = atomicAdd(&cursor[dst[i]], 1);
        esorted[p] = src[i];
    }
}

// mqc[r][c] = (x[r]·W1[:,c]) * dinv[r]  stored bf16.
// block 256 = 32 rows x 8 lanes; lane owns 4 cols (float4 accumulate).
#define XLD 132   // 132 % 32 == 4 -> rows hit different banks; 33 float4s
__global__ void gemm1_kernel(const float* __restrict__ x, const float* __restrict__ W1,
                             const float* __restrict__ dinv,
                             unsigned short* __restrict__ mqc, int n) {
    __shared__ float  Xl[32 * XLD];
    __shared__ float4 Wl4[DIN * 8];

    int t = threadIdx.x;
    for (int i = t; i < DIN * 8; i += 256) Wl4[i] = ((const float4*)W1)[i];

    int rb = blockIdx.x * 32;
    for (int i = t; i < 32 * 32; i += 256) {      // 32 rows x 32 float4
        int rr = i >> 5, c4 = i & 31;
        int gr = rb + rr;
        float4 v = make_float4(0.f, 0.f, 0.f, 0.f);
        if (gr < n) v = ((const float4*)x)[(size_t)gr * 32 + c4];
        ((float4*)Xl)[rr * 33 + c4] = v;
    }
    __syncthreads();

    const int lane = t & 7;        // 4 cols each
    const int row  = t >> 3;       // 0..31
    const float* xrow = &Xl[row * XLD];
    float4 acc = make_float4(0.f, 0.f, 0.f, 0.f);
#pragma unroll
    for (int k = 0; k < DIN; ++k) {
        float xv = xrow[k];
        float4 w = Wl4[k * 8 + lane];
        acc.x += xv * w.x; acc.y += xv * w.y;
        acc.z += xv * w.z; acc.w += xv * w.w;
    }
    int r = rb + row;
    if (r < n) {
        float di = dinv[r];
        unsigned short* p = &mqc[(size_t)r * DH + 4 * lane];
        p[0] = f2bf(acc.x * di); p[1] = f2bf(acc.y * di);
        p[2] = f2bf(acc.z * di); p[3] = f2bf(acc.w * di);
    }
}

// fused layer-1 gather + ReLU + W2 transform.  32 lanes per node, lane = dim.
__global__ void gather1_kernel(const int* __restrict__ cursor, const int* __restrict__ cnt,
                               const int* __restrict__ esorted,
                               const unsigned short* __restrict__ mqc,
                               const float* __restrict__ dinv,
                               const float* __restrict__ b1, const float* __restrict__ W2,
                               float2* __restrict__ m2q, int n) {
    int t = threadIdx.x;
    int lane = t & 31;
    int r = blockIdx.x * 8 + (t >> 5);
    if (r >= n) return;
    int end = cursor[r];
    int beg = end - cnt[r];
    float acc = bf2f(mqc[(size_t)r * DH + lane]);    // self loop
    for (int base = beg; base < end; base += 32) {
        int m = end - base; if (m > 32) m = 32;
        int sv = (base + lane < end) ? esorted[base + lane] : 0;
        for (int u = 0; u < m; ++u) {
            int s = __shfl(sv, u, 32);
            acc += bf2f(mqc[(size_t)s * DH + lane]);
        }
    }
    float di = dinv[r];
    float h = fmaxf(di * acc + b1[lane], 0.0f);
    float p0 = h * W2[lane * DOUT + 0];
    float p1 = h * W2[lane * DOUT + 1];
#pragma unroll
    for (int off = 16; off > 0; off >>= 1) {
        p0 += __shfl_down(p0, off, 32);
        p1 += __shfl_down(p1, off, 32);
    }
    if (lane == 0) m2q[r] = make_float2(di * p0, di * p1);
}

// layer-2 gather + bias: one thread per node.
__global__ void gather2_kernel(const int* __restrict__ cursor, const int* __restrict__ cnt,
                               const int* __restrict__ esorted,
                               const float2* __restrict__ m2q,
                               const float* __restrict__ dinv, const float* __restrict__ b2,
                               float* __restrict__ out, int n) {
    int r = blockIdx.x * blockDim.x + threadIdx.x;
    if (r >= n) return;
    int end = cursor[r];
    int beg = end - cnt[r];
    float2 self = m2q[r];
    float a0 = self.x, a1 = self.y;
    for (int tt = beg; tt < end; ++tt) {
        int s = esorted[tt];
        float2 v = m2q[s];
        a0 += v.x; a1 += v.y;
    }
    float di = dinv[r];
    out[(size_t)r * DOUT + 0] = di * a0 + b2[0];
    out[(size_t)r * DOUT + 1] = di * a1 + b2[1];
}

extern "C" void kernel_launch(void* const* d_in, const int* in_sizes, int n_in,
                              void* d_out, int out_size, void* d_ws, size_t ws_size,
                              hipStream_t stream) {
    const float* x  = (const float*)d_in[0];
    const int*   ei = (const int*)d_in[1];
    const float* W1 = (const float*)d_in[2];
    const float* b1 = (const float*)d_in[3];
    const float* W2 = (const float*)d_in[4];
    const float* b2 = (const float*)d_in[5];
    float* out = (float*)d_out;

    const int n = in_sizes[0] / DIN;
    const int e = in_sizes[1] / 2;
    const int* src = ei;
    const int* dst = ei + e;

    char* ws = (char*)d_ws;
    int*   cnt     = (int*)ws;                         ws += (size_t)n * 4;
    int*   cursor  = (int*)ws;                         ws += (size_t)n * 4;
    int*   bsum    = (int*)ws;                         ws += 256 * 4;
    int*   esorted = (int*)ws;                         ws += (size_t)e * 4;
    float* dinv    = (float*)ws;                       ws += (size_t)n * 4;
    float2* m2q    = (float2*)ws;                      ws += (size_t)n * 8;
    unsigned short* mqc = (unsigned short*)ws;         // n*32*2 bytes

    const int B = 256;
    const int nb = (n + 1023) / 1024;   // scan blocks (98 for n=100000)

    zero_cnt_kernel<<<(n + B - 1) / B, B, 0, stream>>>(cnt, n);
    hist_kernel<<<(e + B - 1) / B, B, 0, stream>>>(dst, cnt, e);
    scanA_kernel<<<nb, B, 0, stream>>>(cnt, cursor, bsum, dinv, n);
    scanB_kernel<<<1, B, 0, stream>>>(bsum, nb);
    scanC_kernel<<<nb, B, 0, stream>>>(cursor, bsum, n);
    fill_kernel<<<(e + B - 1) / B, B, 0, stream>>>(src, dst, cursor, esorted, e);
    gemm1_kernel<<<(n + 31) / 32, B, 0, stream>>>(x, W1, dinv, mqc, n);
    gather1_kernel<<<(n + 7) / 8, B, 0, stream>>>(cursor, cnt, esorted, mqc, dinv, b1, W2, m2q, n);
    gather2_kernel<<<(n + B - 1) / B, B, 0, stream>>>(cursor, cnt, esorted, m2q, dinv, b2, out, n);
}